// Round 4
// baseline (848.519 us; speedup 1.0000x reference)
//
#include <hip/hip_runtime.h>
#include <hip/hip_bf16.h>

#define BB 128
#define NN 2048
#define DD 128
#define HH 8

// ws layout (float offsets)
#define GSUM_OFF 0            // B*D = 16384 (zeroed)
#define ESUM_OFF 16384        // B*H = 1024 (zeroed)
#define WQE_OFF  17408        // B*(H*D) = 131072
#define SB_OFF   148480       // B*H = 1024
#define PT_OFF   149504       // Pt[e][m] 384*128 = 49152
#define PB_OFF   198656       // 128
#define E_OFF    262144       // B*H*N = 2097152

// ---------- K1: gsum[b][d] = sum_n x[b][n][d] ----------
__launch_bounds__(256)
__global__ void k1_gsum(const float* __restrict__ x, float* __restrict__ gsum) {
    int b = blockIdx.y, cx = blockIdx.x, t = threadIdx.x;
    int c4 = t & 31, rg = t >> 5;
    const float4* x4 = (const float4*)(x + ((size_t)b * NN + cx * 256) * DD);
    float4 acc = make_float4(0.f, 0.f, 0.f, 0.f);
    #pragma unroll 8
    for (int i = 0; i < 32; ++i) {
        float4 v = x4[(size_t)(rg + 8 * i) * 32 + c4];
        acc.x += v.x; acc.y += v.y; acc.z += v.z; acc.w += v.w;
    }
    acc.x += __shfl_xor(acc.x, 32, 64);
    acc.y += __shfl_xor(acc.y, 32, 64);
    acc.z += __shfl_xor(acc.z, 32, 64);
    acc.w += __shfl_xor(acc.w, 32, 64);
    __shared__ float xsum[4][32][4];
    int w = t >> 6, lane = t & 63;
    if (lane < 32) {
        xsum[w][lane][0] = acc.x; xsum[w][lane][1] = acc.y;
        xsum[w][lane][2] = acc.z; xsum[w][lane][3] = acc.w;
    }
    __syncthreads();
    if (t < 32) {
        #pragma unroll
        for (int comp = 0; comp < 4; ++comp) {
            float s = xsum[0][t][comp] + xsum[1][t][comp] + xsum[2][t][comp] + xsum[3][t][comp];
            atomicAdd(&gsum[b * DD + t * 4 + comp], s);
        }
    }
}

// ---------- K2a: Pt[e][m] = sum_r Wq[m][r]*Wl[r][e];  pb[m] = Wq[m]·bl + bq[m] ----------
__global__ void k2a(const float* __restrict__ Wq, const float* __restrict__ Wl,
                    const float* __restrict__ bl, const float* __restrict__ bq,
                    float* ws) {
    __shared__ float wqL[128];
    int m = blockIdx.x, t = threadIdx.x;   // 384 threads = e
    if (t < 128) wqL[t] = Wq[m * 128 + t];
    __syncthreads();
    float acc = 0.f;
    #pragma unroll 8
    for (int r = 0; r < 128; ++r) acc = fmaf(wqL[r], Wl[(size_t)r * 384 + t], acc);
    ws[PT_OFF + (size_t)t * 128 + m] = acc;   // transposed store (m fastest for k2b coalescing)
    if (t == 0) {
        float pb = bq[m];
        for (int r = 0; r < 128; ++r) pb = fmaf(wqL[r], bl[r], pb);
        ws[PB_OFF + m] = pb;
    }
}

// ---------- K2b: per b: ctx -> qv = Pt·ctx + pb -> wqe[h][d] = 0.25 * Wk-fold(qv); sb[h] ----------
__launch_bounds__(256)
__global__ void k2b(const float* __restrict__ x,
                    const int* __restrict__ fn_p, const int* __restrict__ cn_p,
                    const float* __restrict__ Wk, const float* __restrict__ bk,
                    float* ws) {
    __shared__ float ctxL[384];
    __shared__ float qpart[2][128];
    __shared__ float qvL[128];
    int b = blockIdx.x, t = threadIdx.x;  // 256 threads
    bool is64 = (fn_p[1] == 0 && fn_p[3] == 0 && fn_p[5] == 0 && fn_p[7] == 0 &&
                 cn_p[1] == 0 && cn_p[3] == 0 && cn_p[5] == 0 && cn_p[7] == 0);
    int fn = is64 ? fn_p[2 * b] : fn_p[b];
    int cn = is64 ? cn_p[2 * b] : cn_p[b];
    const float* gsum = ws + GSUM_OFF;
    if (t < 128) {
        ctxL[t]       = gsum[b * DD + t] * (1.0f / NN);
        ctxL[256 + t] = x[((size_t)b * NN + cn) * DD + t];
    } else {
        int u = t - 128;
        ctxL[128 + u] = x[((size_t)b * NN + fn) * DD + u];
    }
    __syncthreads();

    // qv[m] = sum_e Pt[e][m]*ctx[e] + pb[m], split e-range across two halves
    int m = t & 127, half = t >> 7;
    const float* Pt = ws + PT_OFF;
    float part = 0.f;
    int e0 = half * 192;
    #pragma unroll 8
    for (int e = 0; e < 192; ++e) part = fmaf(Pt[(size_t)(e0 + e) * 128 + m], ctxL[e0 + e], part);
    qpart[half][m] = part;
    __syncthreads();
    if (t < 128) qvL[m] = qpart[0][m] + qpart[1][m] + ws[PB_OFF + m];
    __syncthreads();

    // wqe[h][d] = 0.25 * sum_j qv[h*16+j] * Wk[(h*16+j)][d]
    float* wqe = ws + WQE_OFF + (size_t)b * (HH * DD);
    #pragma unroll
    for (int i = t; i < 1024; i += 256) {
        int h = i >> 7, d = i & 127;
        float s = 0.f;
        #pragma unroll
        for (int j = 0; j < 16; ++j)
            s = fmaf(qvL[h * 16 + j], Wk[(size_t)(h * 16 + j) * 128 + d], s);
        wqe[i] = 0.25f * s;
    }
    if (t < HH) {
        float s = 0.f;
        #pragma unroll
        for (int j = 0; j < 16; ++j) s = fmaf(qvL[t * 16 + j], bk[t * 16 + j], s);
        (ws + SB_OFF)[b * HH + t] = 0.25f * s;
    }
}

// mask layout: 0 = byte (np.bool_), 1 = int32, 2 = int64
__device__ __forceinline__ int detect_mask_kind(const int* mw) {
    int big = 0, oddnz = 0;
    #pragma unroll 8
    for (int i = 0; i < 64; ++i) {
        unsigned w = (unsigned)mw[i];
        if (w > 1u) big = 1;
        if ((i & 1) && w != 0u) oddnz = 1;
    }
    return big ? 0 : (oddnz ? 1 : 2);
}
__device__ __forceinline__ int mask_at(const unsigned char* mb, const int* mw, int kind, size_t idx) {
    if (kind == 0) return mb[idx];
    if (kind == 1) return mw[idx];
    return mw[2 * idx];
}

// ---------- K3: e[b][h][n] = mask ? 0 : exp(x[b,n]·wqe[b,h] + sb[b,h]) ----------
// One row per thread; x -> registers (2-deep double buffer); weights via LDS uniform broadcast.
__launch_bounds__(256, 4)
__global__ void k3(const float* __restrict__ x, const void* __restrict__ mask,
                   const float* __restrict__ ws_ro,
                   float* __restrict__ wse, float* __restrict__ esum) {
    __shared__ float4 wq4[256];   // wqe[b] as float4[h*32 + e4]
    __shared__ float sbL[8];
    int b = blockIdx.y, cx = blockIdx.x, t = threadIdx.x;  // grid (8, B)
    const float4* wqe4 = (const float4*)(ws_ro + WQE_OFF + (size_t)b * 1024);
    if (t < 256) wq4[t] = wqe4[t];
    if (t < 8) sbL[t] = (ws_ro + SB_OFF)[b * HH + t];
    __syncthreads();

    const unsigned char* mb = (const unsigned char*)mask;
    const int* mw = (const int*)mask;
    int mkind = detect_mask_kind(mw);

    int n = cx * 256 + t;
    const float4* xr = (const float4*)(x + ((size_t)b * NN + n) * DD);

    float acc[8];
    #pragma unroll
    for (int h = 0; h < HH; ++h) acc[h] = sbL[h];

    float4 bufA[8], bufB[8];
    #pragma unroll
    for (int q = 0; q < 8; ++q) bufA[q] = xr[q];                 // p=0

    #define COMPUTE(BUF, P)                                                   \
        {                                                                     \
            _Pragma("unroll")                                                 \
            for (int h = 0; h < HH; ++h) {                                    \
                _Pragma("unroll")                                             \
                for (int q = 0; q < 8; ++q) {                                 \
                    float4 w = wq4[h * 32 + (P) * 8 + q];                     \
                    acc[h] += BUF[q].x * w.x + BUF[q].y * w.y +               \
                              BUF[q].z * w.z + BUF[q].w * w.w;                \
                }                                                             \
            }                                                                 \
        }

    #pragma unroll
    for (int q = 0; q < 8; ++q) bufB[q] = xr[8 + q];             // p=1 prefetch
    COMPUTE(bufA, 0)
    #pragma unroll
    for (int q = 0; q < 8; ++q) bufA[q] = xr[16 + q];            // p=2 prefetch
    COMPUTE(bufB, 1)
    #pragma unroll
    for (int q = 0; q < 8; ++q) bufB[q] = xr[24 + q];            // p=3 prefetch
    COMPUTE(bufA, 2)
    COMPUTE(bufB, 3)
    #undef COMPUTE

    int msk = mask_at(mb, mw, mkind, (size_t)b * NN + n);
    float ev[8];
    #pragma unroll
    for (int h = 0; h < HH; ++h) {
        ev[h] = msk ? 0.f : __expf(acc[h]);
        wse[((size_t)(b * HH + h)) * NN + n] = ev[h];
    }
    int lane = t & 63;
    #pragma unroll
    for (int h = 0; h < HH; ++h) {
        float v = ev[h];
        #pragma unroll
        for (int off = 32; off >= 1; off >>= 1) v += __shfl_xor(v, off, 64);
        if (lane == 0) atomicAdd(&esum[b * HH + h], v);
    }
}

// ---------- K4: out[b][n] = sum_h e[b][h][n] * (0.125/esum[b][h]) ----------
__global__ void k4_out(const float* __restrict__ wse, const float* __restrict__ esum,
                       float* __restrict__ out) {
    __shared__ float rinv[8];
    int b = blockIdx.y, cx = blockIdx.x, t = threadIdx.x;
    if (t < 8) rinv[t] = 0.125f / esum[b * HH + t];
    __syncthreads();
    int n = cx * 256 + t;
    float o = 0.f;
    #pragma unroll
    for (int h = 0; h < HH; ++h)
        o += wse[((size_t)(b * HH + h)) * NN + n] * rinv[h];
    out[(size_t)b * NN + n] = o;
}

extern "C" void kernel_launch(void* const* d_in, const int* in_sizes, int n_in,
                              void* d_out, int out_size, void* d_ws, size_t ws_size,
                              hipStream_t stream) {
    const float* x  = (const float*)d_in[0];
    const int* fn   = (const int*)d_in[1];
    const int* cn   = (const int*)d_in[2];
    const void* mk  = d_in[3];
    const float* Wl = (const float*)d_in[4];
    const float* bl = (const float*)d_in[5];
    const float* Wq = (const float*)d_in[6];
    const float* bq = (const float*)d_in[7];
    const float* Wk = (const float*)d_in[8];
    const float* bk = (const float*)d_in[9];
    float* ws  = (float*)d_ws;
    float* out = (float*)d_out;

    // zero gsum + esum accumulators
    hipMemsetAsync(d_ws, 0, (size_t)(16384 + 1024) * 4, stream);

    k1_gsum<<<dim3(8, BB), 256, 0, stream>>>(x, ws + GSUM_OFF);
    k2a<<<128, 384, 0, stream>>>(Wq, Wl, bl, bq, ws);
    k2b<<<BB, 256, 0, stream>>>(x, fn, cn, Wk, bk, ws);
    k3<<<dim3(8, BB), 256, 0, stream>>>(x, mk, ws, ws + E_OFF, ws + ESUM_OFF);
    k4_out<<<dim3(8, BB), 256, 0, stream>>>(ws + E_OFF, ws + ESUM_OFF, out);
}

// Round 5
// 259.501 us; speedup vs baseline: 3.2698x; 3.2698x over previous
//
#include <hip/hip_runtime.h>
#include <hip/hip_bf16.h>

#define BB 128
#define NN 2048
#define DD 128
#define HH 8

// ws float offsets (no zero-init required anywhere)
#define GSP_OFF  0          // [B][8][128] k1 partial sums = 131072
#define WQE_OFF  131072     // [B][H*128]  = 131072
#define SB_OFF   262144     // [B][H]      = 1024
#define ESP_OFF  263168     // [B][8][H]   k3 partial esums = 8192
#define E_OFF    271360     // [B][N][H]   = 2097152

// ---------- K1: gsp[b][cx][d] = sum over 256 rows of x[b][n][d] ----------
__launch_bounds__(256)
__global__ void k1_gsum(const float* __restrict__ x, float* __restrict__ gsp) {
    int b = blockIdx.y, cx = blockIdx.x, t = threadIdx.x;
    int c4 = t & 31, rg = t >> 5;                       // 32 float4-cols x 8 row-groups
    const float4* x4 = (const float4*)(x + ((size_t)b * NN + cx * 256) * DD);
    float4 acc = make_float4(0.f, 0.f, 0.f, 0.f);
    #pragma unroll 8
    for (int i = 0; i < 32; ++i) {
        float4 v = x4[(size_t)(rg + 8 * i) * 32 + c4];
        acc.x += v.x; acc.y += v.y; acc.z += v.z; acc.w += v.w;
    }
    // lanes l and l^32 share c4 (rg pair) -> combine in-wave
    acc.x += __shfl_xor(acc.x, 32, 64);
    acc.y += __shfl_xor(acc.y, 32, 64);
    acc.z += __shfl_xor(acc.z, 32, 64);
    acc.w += __shfl_xor(acc.w, 32, 64);
    __shared__ float xsum[4][32][4];
    int w = t >> 6, lane = t & 63;
    if (lane < 32) {
        xsum[w][lane][0] = acc.x; xsum[w][lane][1] = acc.y;
        xsum[w][lane][2] = acc.z; xsum[w][lane][3] = acc.w;
    }
    __syncthreads();
    if (t < 32) {
        float4 s;
        s.x = xsum[0][t][0] + xsum[1][t][0] + xsum[2][t][0] + xsum[3][t][0];
        s.y = xsum[0][t][1] + xsum[1][t][1] + xsum[2][t][1] + xsum[3][t][1];
        s.z = xsum[0][t][2] + xsum[1][t][2] + xsum[2][t][2] + xsum[3][t][2];
        s.w = xsum[0][t][3] + xsum[1][t][3] + xsum[2][t][3] + xsum[3][t][3];
        ((float4*)(gsp + ((size_t)b * 8 + cx) * 128))[t] = s;   // no atomics
    }
}

// ---------- K2 (fused): ctx -> q_in = Wl*ctx+bl -> q = Wq*q_in+bq -> wqe,sb ----------
__launch_bounds__(256)
__global__ void k2(const float* __restrict__ x,
                   const int* __restrict__ fn_p, const int* __restrict__ cn_p,
                   const float* __restrict__ Wl, const float* __restrict__ bl,
                   const float* __restrict__ Wq, const float* __restrict__ bq,
                   const float* __restrict__ Wk, const float* __restrict__ bk,
                   float* ws) {
    __shared__ float ctxL[384];
    __shared__ float qpart[2][128];
    __shared__ float qinL[128];
    __shared__ float qvL[128];
    int b = blockIdx.x, t = threadIdx.x;  // 256 threads
    // int64 vs int32 index-layout hedge (values < 2^31 -> odd words zero if int64)
    bool is64 = (fn_p[1] == 0 && fn_p[3] == 0 && fn_p[5] == 0 && fn_p[7] == 0 &&
                 cn_p[1] == 0 && cn_p[3] == 0 && cn_p[5] == 0 && cn_p[7] == 0);
    int fn = is64 ? fn_p[2 * b] : fn_p[b];
    int cn = is64 ? cn_p[2 * b] : cn_p[b];

    const float* gsp = ws + GSP_OFF + (size_t)b * 8 * 128;
    if (t < 128) {
        float g = 0.f;
        #pragma unroll
        for (int i = 0; i < 8; ++i) g += gsp[i * 128 + t];
        ctxL[t]       = g * (1.0f / NN);
        ctxL[256 + t] = x[((size_t)b * NN + cn) * DD + t];
    } else {
        int u = t - 128;
        ctxL[128 + u] = x[((size_t)b * NN + fn) * DD + u];
    }
    __syncthreads();

    // q_in[m] = bl[m] + sum_e ctx[e]*Wl[m][e], e split across two halves
    int m = t & 127, half = t >> 7;
    {
        const float* wrow = Wl + (size_t)m * 384 + half * 192;
        const float* cp = ctxL + half * 192;
        float part = 0.f;
        #pragma unroll 8
        for (int e = 0; e < 192; ++e) part = fmaf(wrow[e], cp[e], part);
        qpart[half][m] = part;
    }
    __syncthreads();
    if (t < 128) qinL[t] = qpart[0][t] + qpart[1][t] + bl[t];
    __syncthreads();

    // q[r] = bq[r] + sum_c q_in[c]*Wq[r][c]
    {
        const float* wrow = Wq + (size_t)m * 128 + half * 64;
        const float* cp = qinL + half * 64;
        float part = 0.f;
        #pragma unroll 8
        for (int c = 0; c < 64; ++c) part = fmaf(wrow[c], cp[c], part);
        qpart[half][m] = part;
    }
    __syncthreads();
    if (t < 128) qvL[t] = qpart[0][t] + qpart[1][t] + bq[t];
    __syncthreads();

    // wqe[h][d] = 0.25 * sum_j qv[h*16+j]*Wk[h*16+j][d]
    float* wqe = ws + WQE_OFF + (size_t)b * (HH * DD);
    #pragma unroll
    for (int i = t; i < 1024; i += 256) {
        int h = i >> 7, d = i & 127;
        float s = 0.f;
        #pragma unroll
        for (int j = 0; j < 16; ++j)
            s = fmaf(qvL[h * 16 + j], Wk[(size_t)(h * 16 + j) * 128 + d], s);
        wqe[i] = 0.25f * s;
    }
    if (t < HH) {
        float s = 0.f;
        #pragma unroll
        for (int j = 0; j < 16; ++j) s = fmaf(qvL[t * 16 + j], bk[t * 16 + j], s);
        (ws + SB_OFF)[b * HH + t] = 0.25f * s;
    }
}

// mask layout: 0 = byte (np.bool_), 1 = int32, 2 = int64
__device__ __forceinline__ int detect_mask_kind(const int* mw) {
    int big = 0, oddnz = 0;
    #pragma unroll 8
    for (int i = 0; i < 64; ++i) {
        unsigned w = (unsigned)mw[i];
        if (w > 1u) big = 1;
        if ((i & 1) && w != 0u) oddnz = 1;
    }
    return big ? 0 : (oddnz ? 1 : 2);
}
__device__ __forceinline__ int mask_at(const unsigned char* mb, const int* mw, int kind, size_t idx) {
    if (kind == 0) return mb[idx];
    if (kind == 1) return mw[idx];
    return mw[2 * idx];
}

// ---------- K3: e[b][n][h] = mask ? 0 : exp(x[b,n]·wqe[b,h] + sb[b,h]); esp partials ----------
// 1 row/thread, tight q-loop (<=4 float4 in flight), weights via LDS uniform broadcast.
__global__ void k3(const float* __restrict__ x, const void* __restrict__ mask,
                   const float* __restrict__ ws_ro,
                   float* __restrict__ wse, float* __restrict__ esp) {
    __shared__ float4 wq4[256];     // wqe[b]: [h][q] as float4
    __shared__ float sbL[8];
    __shared__ float ps[4][8];
    int b = blockIdx.y, cx = blockIdx.x, t = threadIdx.x;   // grid (8, B), 256 thr
    const float4* wqe4 = (const float4*)(ws_ro + WQE_OFF + (size_t)b * 1024);
    wq4[t] = wqe4[t];
    if (t < 8) sbL[t] = (ws_ro + SB_OFF)[b * HH + t];
    __syncthreads();

    const unsigned char* mb = (const unsigned char*)mask;
    const int* mw = (const int*)mask;
    int mkind = detect_mask_kind(mw);

    int n = cx * 256 + t;
    const float4* xr = (const float4*)(x + ((size_t)b * NN + n) * DD);

    float acc[HH];
    #pragma unroll
    for (int h = 0; h < HH; ++h) acc[h] = sbL[h];

    #pragma unroll 4
    for (int q = 0; q < 32; ++q) {
        float4 v = xr[q];
        #pragma unroll
        for (int h = 0; h < HH; ++h) {
            float4 w = wq4[h * 32 + q];
            acc[h] = fmaf(v.x, w.x, fmaf(v.y, w.y, fmaf(v.z, w.z, fmaf(v.w, w.w, acc[h]))));
        }
    }

    int msk = mask_at(mb, mw, mkind, (size_t)b * NN + n);
    float ev[HH];
    #pragma unroll
    for (int h = 0; h < HH; ++h) ev[h] = msk ? 0.f : __expf(acc[h]);

    float4 E0 = make_float4(ev[0], ev[1], ev[2], ev[3]);
    float4 E1 = make_float4(ev[4], ev[5], ev[6], ev[7]);
    float4* wp = (float4*)(wse + ((size_t)b * NN + n) * 8);
    wp[0] = E0; wp[1] = E1;

    int w = t >> 6, lane = t & 63;
    #pragma unroll
    for (int h = 0; h < HH; ++h) {
        float v = ev[h];
        #pragma unroll
        for (int off = 32; off >= 1; off >>= 1) v += __shfl_xor(v, off, 64);
        if (lane == 0) ps[w][h] = v;
    }
    __syncthreads();
    if (t < 8)
        esp[((size_t)b * 8 + cx) * 8 + t] = ps[0][t] + ps[1][t] + ps[2][t] + ps[3][t];
}

// ---------- K4: out[b][n] = sum_h e[b][n][h] * (0.125/esum[b][h]) ----------
__global__ void k4_out(const float* __restrict__ wse, const float* __restrict__ esp,
                       float* __restrict__ out) {
    __shared__ float rinv[8];
    int b = blockIdx.y, cx = blockIdx.x, t = threadIdx.x;
    if (t < 8) {
        float s = 0.f;
        #pragma unroll
        for (int i = 0; i < 8; ++i) s += esp[((size_t)b * 8 + i) * 8 + t];
        rinv[t] = 0.125f / s;
    }
    __syncthreads();
    int n = cx * 256 + t;
    const float4* ep = (const float4*)(wse + ((size_t)b * NN + n) * 8);
    float4 e0 = ep[0], e1 = ep[1];
    out[(size_t)b * NN + n] =
        e0.x * rinv[0] + e0.y * rinv[1] + e0.z * rinv[2] + e0.w * rinv[3] +
        e1.x * rinv[4] + e1.y * rinv[5] + e1.z * rinv[6] + e1.w * rinv[7];
}

extern "C" void kernel_launch(void* const* d_in, const int* in_sizes, int n_in,
                              void* d_out, int out_size, void* d_ws, size_t ws_size,
                              hipStream_t stream) {
    const float* x  = (const float*)d_in[0];
    const int* fn   = (const int*)d_in[1];
    const int* cn   = (const int*)d_in[2];
    const void* mk  = d_in[3];
    const float* Wl = (const float*)d_in[4];
    const float* bl = (const float*)d_in[5];
    const float* Wq = (const float*)d_in[6];
    const float* bq = (const float*)d_in[7];
    const float* Wk = (const float*)d_in[8];
    const float* bk = (const float*)d_in[9];
    float* ws  = (float*)d_ws;
    float* out = (float*)d_out;

    k1_gsum<<<dim3(8, BB), 256, 0, stream>>>(x, ws + GSP_OFF);
    k2<<<BB, 256, 0, stream>>>(x, fn, cn, Wl, bl, Wq, bq, Wk, bk, ws);
    k3<<<dim3(8, BB), 256, 0, stream>>>(x, mk, ws, ws + E_OFF, ws + ESP_OFF);
    k4_out<<<dim3(8, BB), 256, 0, stream>>>(ws + E_OFF, ws + ESP_OFF, out);
}